// Round 3
// baseline (553.668 us; speedup 1.0000x reference)
//
#include <hip/hip_runtime.h>
#include <stdint.h>
#include <stddef.h>

// DKVMN: B=64,T=100, DK=DV=N=128, NUM_Q=1000.  f32 in / f32 out (bf16 I/O fails).
// Decomposition v4 — zero barriers in the T=100 scan:
//   kernel A : state-independent w/e/a/ftk for all (b,t); shuffle softmax.
//   kernel B1: Mv recurrence, pure elementwise streamer. Thread owns (n, 4d),
//              m[4] in regs, 1-step prefetch, nontemporal float4 stores, XCD
//              swizzle. No LDS/barrier/shuffle -> streams at write BW.
//   kernel B2: rt computed by RE-RUNNING the recurrence in a second geometry:
//              one wave spans all 128 n (2 n/lane x 4 d/lane, m in 8 regs);
//              rt[d] = sum_n w[n]*m[n,d] via 6-level shfl_xor butterfly.
//              No LDS, no barrier, writes FINAL rt (3.3 MB, not partials).
//              Butterfly is off the critical path (next step needs only m).
//   kernel C : p from rt (reads 2 KB/bt), 4 timesteps/block, shuffle reduce.
// Rationale: v3 measured 504us vs ~110us structural floor; per-step
// __syncthreads forces s_waitcnt vmcnt(0) draining the HBM store each of the
// 100 steps. This version has no barrier anywhere in the scan.
// ws usage: 4*WSTRIDE + BT*D floats = 16.5 MB.

constexpr int B = 64;
constexpr int T = 100;
constexpr int D = 128;        // DK = DV = N
constexpr int NUM_Q = 1000;
constexpr int G = 4;          // timesteps per block in kernel A
constexpr int CG = 4;         // timesteps per block in kernel C
constexpr int BT = B * T;     // 6400
constexpr int WSTRIDE = BT * D; // 819200 floats per ws plane

typedef float v4f __attribute__((ext_vector_type(4)));

__device__ __forceinline__ float sigmoidf_(float x) {
  return 1.0f / (1.0f + __expf(-x));
}

// ---------------- Kernel A: per-(b,t) precompute w, e, a, ftk ----------------
__global__ __launch_bounds__(128) void kernelA(
    const int* __restrict__ q, const int* __restrict__ r,
    const float* __restrict__ k_emb, const float* __restrict__ v_emb,
    const float* __restrict__ Mk,
    const float* __restrict__ f_W, const float* __restrict__ f_b,
    const float* __restrict__ e_W, const float* __restrict__ e_b,
    const float* __restrict__ a_W, const float* __restrict__ a_b,
    float* __restrict__ ws_w, float* __restrict__ ws_e,
    float* __restrict__ ws_a, float* __restrict__ ws_f)
{
  const int tid = threadIdx.x;
  const int b  = blockIdx.x / (T / G);
  const int tg = blockIdx.x % (T / G);
  const int tbase = tg * G;

  __shared__ float kt[G][D];
  __shared__ float vt[G][D];
  __shared__ float redm[2], reds[2];

  #pragma unroll
  for (int g = 0; g < G; ++g) {
    int idx = b * T + tbase + g;
    int qi  = q[idx];
    int qri = qi + NUM_Q * r[idx];
    kt[g][tid] = k_emb[qi * D + tid];
    vt[g][tid] = v_emb[qri * D + tid];
  }
  __syncthreads();

  float lg[G], se[G], sa[G], sf[G];
  #pragma unroll
  for (int g = 0; g < G; ++g) { lg[g] = 0.f; se[g] = 0.f; sa[g] = 0.f; sf[g] = 0.f; }

  #pragma unroll 4
  for (int k = 0; k < D; ++k) {
    float mk = Mk[k * D + tid];
    float ew = e_W[k * D + tid];
    float aw = a_W[k * D + tid];
    float fw = f_W[(D + k) * D + tid];   // kt-half of f_W (rows 128..255)
    #pragma unroll
    for (int g = 0; g < G; ++g) {
      float kk = kt[g][k];
      float vv = vt[g][k];
      lg[g] = fmaf(kk, mk, lg[g]);
      se[g] = fmaf(vv, ew, se[g]);
      sa[g] = fmaf(vv, aw, sa[g]);
      sf[g] = fmaf(kk, fw, sf[g]);
    }
  }

  const float eb = e_b[tid];
  const float ab = a_b[tid];
  const float fb = f_b[tid];

  for (int g = 0; g < G; ++g) {
    // softmax over 128 logits: wave shuffle reduce + 2-wave LDS combine
    float v = lg[g];
    #pragma unroll
    for (int s = 32; s > 0; s >>= 1) v = fmaxf(v, __shfl_xor(v, s));
    if ((tid & 63) == 0) redm[tid >> 6] = v;
    __syncthreads();
    float mx = fmaxf(redm[0], redm[1]);
    float ex = __expf(lg[g] - mx);
    v = ex;
    #pragma unroll
    for (int s = 32; s > 0; s >>= 1) v += __shfl_xor(v, s);
    if ((tid & 63) == 0) reds[tid >> 6] = v;
    __syncthreads();
    float sm = reds[0] + reds[1];

    int idx = (b * T + tbase + g) * D + tid;
    ws_w[idx] = ex / sm;
    ws_e[idx] = sigmoidf_(se[g] + eb);
    ws_a[idx] = tanhf(sa[g] + ab);
    ws_f[idx] = sf[g] + fb;
  }
}

// ---------------- Kernel B1: Mv streamer (no LDS, no barrier) ----------------
// block: 256 threads = 8 n-rows x 32 d-groups(4 floats); grid: 1024 (B x 16 n-tiles)
// XCD swizzle: j&7 carries b-high, so each XCD's L2 holds only its 8 batches.
__global__ __launch_bounds__(256) void kernelB1(
    const float* __restrict__ Mv0,
    const float* __restrict__ ws_w, const float* __restrict__ ws_e,
    const float* __restrict__ ws_a,
    float* __restrict__ out_Mv)
{
  const int j = blockIdx.x;
  const int b  = ((j & 7) << 3) | ((j >> 3) & 7);
  const int nt = j >> 6;                            // 0..15
  const int tid = threadIdx.x;
  const int nrow = tid >> 5;                        // 0..7
  const int dgrp = tid & 31;                        // 0..31
  const int n  = nt * 8 + nrow;
  const int d0 = dgrp * 4;

  float m[4];
  #pragma unroll
  for (int i = 0; i < 4; ++i) m[i] = Mv0[n * D + d0 + i];

  const float*  pw = ws_w + (size_t)(b * T) * D + n;
  const float4* pe = (const float4*)(ws_e + (size_t)(b * T) * D + d0);
  const float4* pa = (const float4*)(ws_a + (size_t)(b * T) * D + d0);

  float  wv = pw[0];
  float4 ev = pe[0];
  float4 av = pa[0];

  for (int t = 0; t < T; ++t) {
    const int tn = (t + 1 < T) ? (t + 1) : t;
    float  wn = pw[(size_t)tn * D];
    float4 en = pe[(size_t)tn * 32];
    float4 an = pa[(size_t)tn * 32];

    float ee[4] = {ev.x, ev.y, ev.z, ev.w};
    float aa[4] = {av.x, av.y, av.z, av.w};
    #pragma unroll
    for (int i = 0; i < 4; ++i) {
      m[i] = m[i] * (1.0f - wv * ee[i]) + wv * aa[i];
    }

    size_t obase = ((size_t)(t * B + b) * D + n) * D + d0;
    v4f o0 = {m[0], m[1], m[2], m[3]};
    __builtin_nontemporal_store(o0, (v4f*)(out_Mv + obase));

    wv = wn; ev = en; av = an;
  }
}

// ---------------- Kernel B2: rt via full-wave butterfly ----------------
// One wave spans ALL 128 n: lane owns n={2l,2l+1} x 4 d.  Block 256 = 4 waves
// = 4 d-slices; grid 512 = B x 8 d-quarters.  No LDS, no barrier.
__global__ __launch_bounds__(256) void kernelB2(
    const float* __restrict__ Mv0,
    const float* __restrict__ ws_w, const float* __restrict__ ws_e,
    const float* __restrict__ ws_a,
    float* __restrict__ ws_rt)
{
  const int j = blockIdx.x;
  const int b  = ((j & 7) << 3) | ((j >> 3) & 7);
  const int dq = j >> 6;                            // 0..7
  const int tid = threadIdx.x;
  const int wave = tid >> 6;
  const int lane = tid & 63;
  const int d0 = dq * 16 + wave * 4;                // 4 d per lane
  const int n0 = 2 * lane;                          // lane owns n0, n0+1

  float m0[4], m1[4];
  #pragma unroll
  for (int i = 0; i < 4; ++i) {
    m0[i] = Mv0[n0 * D + d0 + i];
    m1[i] = Mv0[(n0 + 1) * D + d0 + i];
  }

  // w as float2 per lane (coalesced); e/a broadcast (same 4 floats per wave)
  const float2* pw = (const float2*)(ws_w + (size_t)(b * T) * D) + lane;
  const float4* pe = (const float4*)(ws_e + (size_t)(b * T) * D + d0);
  const float4* pa = (const float4*)(ws_a + (size_t)(b * T) * D + d0);

  float2 wv = pw[0];
  float4 ev = pe[0];
  float4 av = pa[0];

  for (int t = 0; t < T; ++t) {
    const int tn = (t + 1 < T) ? (t + 1) : t;
    float2 wn = pw[(size_t)tn * 64];
    float4 en = pe[(size_t)tn * 32];
    float4 an = pa[(size_t)tn * 32];

    // rt partial from PRE-update state
    float pr[4];
    #pragma unroll
    for (int i = 0; i < 4; ++i) pr[i] = wv.x * m0[i] + wv.y * m1[i];
    // butterfly over all 64 lanes -> every lane holds full sum over 128 n
    #pragma unroll
    for (int s = 1; s < 64; s <<= 1) {
      #pragma unroll
      for (int i = 0; i < 4; ++i) pr[i] += __shfl_xor(pr[i], s);
    }
    if (lane == 0) {
      v4f r4 = {pr[0], pr[1], pr[2], pr[3]};
      *(v4f*)(ws_rt + (size_t)(b * T + t) * D + d0) = r4;
    }

    // state update (independent of the butterfly -> steps pipeline)
    float ee[4] = {ev.x, ev.y, ev.z, ev.w};
    float aa[4] = {av.x, av.y, av.z, av.w};
    #pragma unroll
    for (int i = 0; i < 4; ++i) {
      m0[i] = m0[i] * (1.0f - wv.x * ee[i]) + wv.x * aa[i];
      m1[i] = m1[i] * (1.0f - wv.y * ee[i]) + wv.y * aa[i];
    }

    wv = wn; ev = en; av = an;
  }
}

// ---------------- Kernel C: p from rt ----------------
// block: 128 threads, CG=4 timesteps per block; grid: B * T/CG = 1600
__global__ __launch_bounds__(128) void kernelC(
    const float* __restrict__ f_W,
    const float* __restrict__ p_W,
    const float* __restrict__ p_b,
    const float* __restrict__ ws_f, const float* __restrict__ ws_rt,
    float* __restrict__ out_p)
{
  const int grp = blockIdx.x;
  const int b  = grp / (T / CG);
  const int tg = grp % (T / CG);
  const int t0 = tg * CG;
  const int bt0 = b * T + t0;
  const int tid = threadIdx.x;

  __shared__ float rsh[CG][D];
  __shared__ float wred[CG][2];

  float fa[CG];
  #pragma unroll
  for (int g = 0; g < CG; ++g) {
    rsh[g][tid] = ws_rt[(size_t)(bt0 + g) * D + tid];
    fa[g] = ws_f[(bt0 + g) * D + tid];   // ftk = kt-half @ f_W + f_b (from A)
  }
  __syncthreads();

  #pragma unroll 4
  for (int d2 = 0; d2 < D; ++d2) {
    float fw = f_W[d2 * D + tid];        // rt-half of f_W (rows 0..127)
    #pragma unroll
    for (int g = 0; g < CG; ++g) fa[g] = fmaf(rsh[g][d2], fw, fa[g]);
  }

  const float pw = p_W[tid];
  #pragma unroll
  for (int g = 0; g < CG; ++g) {
    float v = tanhf(fa[g]) * pw;
    #pragma unroll
    for (int s = 32; s > 0; s >>= 1) v += __shfl_xor(v, s);
    if ((tid & 63) == 0) wred[g][tid >> 6] = v;
  }
  __syncthreads();
  if (tid < CG) {
    float pt = sigmoidf_(wred[tid][0] + wred[tid][1] + p_b[0]);
    out_p[(t0 + tid) * B + b] = pt;
  }
}

extern "C" void kernel_launch(void* const* d_in, const int* in_sizes, int n_in,
                              void* d_out, int out_size, void* d_ws, size_t ws_size,
                              hipStream_t stream)
{
  const int* q = (const int*)d_in[0];
  const int* r = (const int*)d_in[1];
  const float* k_emb = (const float*)d_in[2];
  const float* v_emb = (const float*)d_in[3];
  const float* Mk   = (const float*)d_in[4];
  const float* Mv0  = (const float*)d_in[5];
  const float* f_W  = (const float*)d_in[6];
  const float* f_b  = (const float*)d_in[7];
  const float* p_W  = (const float*)d_in[8];
  const float* p_b  = (const float*)d_in[9];
  const float* e_W  = (const float*)d_in[10];
  const float* e_b  = (const float*)d_in[11];
  const float* a_W  = (const float*)d_in[12];
  const float* a_b  = (const float*)d_in[13];

  float* ws   = (float*)d_ws;
  float* ws_w = ws;
  float* ws_e = ws + (size_t)WSTRIDE;
  float* ws_a = ws + (size_t)2 * WSTRIDE;
  float* ws_f = ws + (size_t)3 * WSTRIDE;
  float* ws_rt = ws + (size_t)4 * WSTRIDE;   // BT * D floats = 3.3 MB (final rt)

  float* out    = (float*)d_out;
  float* out_p  = out;            // p: first BT elements, layout (T*B,1)
  float* out_Mv = out + BT;       // Mv: (T*B,128,128)

  hipLaunchKernelGGL(kernelA, dim3(B * (T / G)), dim3(D), 0, stream,
                     q, r, k_emb, v_emb, Mk, f_W, f_b, e_W, e_b, a_W, a_b,
                     ws_w, ws_e, ws_a, ws_f);
  hipLaunchKernelGGL(kernelB1, dim3(B * 16), dim3(256), 0, stream,
                     Mv0, ws_w, ws_e, ws_a, out_Mv);
  hipLaunchKernelGGL(kernelB2, dim3(B * 8), dim3(256), 0, stream,
                     Mv0, ws_w, ws_e, ws_a, ws_rt);
  hipLaunchKernelGGL(kernelC, dim3(B * (T / CG)), dim3(D), 0, stream,
                     f_W, p_W, p_b, ws_f, ws_rt, out_p);
}